// Round 10
// baseline (170.304 us; speedup 1.0000x reference)
//
#include <hip/hip_runtime.h>
#include <hip/hip_bf16.h>
#include <stdint.h>

typedef __bf16 bf16_t;
typedef __bf16 bf16x8 __attribute__((ext_vector_type(8)));
typedef __bf16 bf16x4 __attribute__((ext_vector_type(4)));
typedef float f32x4 __attribute__((ext_vector_type(4)));

#define DEVFN static __device__ __forceinline__

DEVFN f32x4 mfma16(bf16x8 a, bf16x8 b, f32x4 c) {
  return __builtin_amdgcn_mfma_f32_16x16x32_bf16(a, b, c, 0, 0, 0);
}

// global -> LDS direct copy, 16B per lane; LDS dest must be wave-uniform.
#define GLL16(gsrc, ldst) __builtin_amdgcn_global_load_lds( \
    (__attribute__((address_space(1))) void*)(gsrc), \
    (__attribute__((address_space(3))) void*)(ldst), 16, 0, 0)

// softmax scale * log2(e), folded into Q at the QKV-GEMM epilogue
#define SCALE_Q 0.1803368801111204f

// ---------------- prep: fp32->bf16 conversion + key compaction (merged) ----------------
__global__ void prep(const float* __restrict__ x, const float* __restrict__ wqkv,
                     const float* __restrict__ wproj, bf16_t* __restrict__ xb,
                     bf16_t* __restrict__ wqkvb, bf16_t* __restrict__ wprojb,
                     const int* __restrict__ mask, int* __restrict__ tc,
                     int* __restrict__ nk, bf16_t* __restrict__ kb,
                     bf16_t* __restrict__ vtb) {
  const int tid = threadIdx.x;
  if (blockIdx.x < 12288) {
    const int i = blockIdx.x * 256 + tid;
    const float* s;
    bf16_t* d;
    int off;
    if (i < 2097152) { s = x; d = xb; off = i; }
    else if (i < 2097152 + 786432) { s = wqkv; d = wqkvb; off = i - 2097152; }
    else { s = wproj; d = wprojb; off = i - 2883584; }
    f32x4 v = reinterpret_cast<const f32x4*>(s)[off];
    bf16x4 o;
    o[0] = (bf16_t)v[0]; o[1] = (bf16_t)v[1]; o[2] = (bf16_t)v[2]; o[3] = (bf16_t)v[3];
    reinterpret_cast<bf16x4*>(d)[off] = o;
    return;
  }
  // ---- compaction ----
  const int b = blockIdx.x - 12288;
  const int lane = tid & 63, wv = tid >> 6;
  __shared__ int nk_s;
  const int* mrow = mask + b * 2048;
  if (wv == 0) {
    int base = 0;
    for (int cs = 0; cs < 2048; cs += 64) {
      const int mval = mrow[cs + lane];
      const unsigned long long bal = __ballot(mval == 0);
      const int pre = __popcll(bal & ((1ull << lane) - 1ull));
      if (!mval) tc[b * 2048 + base + pre] = cs + lane;
      base += __popcll(bal);
    }
    if (lane == 0) nk_s = base;
  }
  __syncthreads();
  const int nkb = nk_s;
  if (tid == 0) nk[b] = nkb;
  for (int i = nkb + tid; i < 2048; i += 256) tc[b * 2048 + i] = -1;
  const int ce = (nkb + 63) & ~63;
  for (int hh = wv; hh < 16; hh += 4) {
    const size_t bh = (size_t)(b * 16 + hh);
    for (int r = nkb; r < ce; ++r) {
      kb[(bh * 2048 + r) * 64 + lane] = (bf16_t)0.f;
      vtb[(bh * 64 + lane) * 2048 + r] = (bf16_t)0.f;
    }
  }
}

// ---------------- QKV GEMM: 8-phase counted-vmcnt 256x256 (T3+T4) ----------------
// C^T = W_qkv[O][K] * x[M][K]^T. 512 threads = 8 waves (2 m-halves x 4 o-quarters),
// per-wave 128m x 64o. LDS 128KB: 2 dbuf x (A 32KB + B 32KB). 4 phases per K-tile:
// { ds_read frags ; 2x global_load_lds(next tile) ; s_barrier ; lgkmcnt(0) ;
//   16 MFMA ; s_barrier }, vmcnt(0) only at tile close. Raw barriers (no
// __syncthreads full drain) keep staging loads in flight across phases.
// Grid 384 = 32 m-tiles x 12 o-tiles, XCD-chunked. bx<4: Q (scaled); 4-7: K; 8-11: V.
__global__ __launch_bounds__(512, 2)
void gemm_qkv8(const bf16_t* __restrict__ A, const bf16_t* __restrict__ Bx,
               bf16_t* __restrict__ qb, bf16_t* __restrict__ kb,
               bf16_t* __restrict__ vtb,
               const int* __restrict__ tc, const int* __restrict__ nkp) {
  constexpr int K = 1024;
  constexpr int NT = 16;  // K-tiles of 64
  __shared__ alignas(16) unsigned short At[2][256 * 64];
  __shared__ alignas(16) unsigned short Bt[2][256 * 64];
  const int tid = threadIdx.x, lane = tid & 63, w = tid >> 6;
  const int c = lane & 15, g = lane >> 4;
  const int bid = blockIdx.x;
  const int xcd = bid & 7, j = bid >> 3;           // 48 blocks per xcd
  const int my = xcd * 4 + (j & 3), bx = j >> 2;   // my [0,32), bx [0,12)
  const int oBase = bx * 256, mBase = my * 256;
  const int wm = (w >> 2) * 128, wo = (w & 3) * 64;
  const int which = bx >> 2;                        // 0=Q 1=K 2=V
  const bool kv = which != 0;
  const int nkb = nkp[mBase >> 11];
  if (kv && (mBase & 2047) >= nkb) return;          // whole tile is pad

  // per-lane B source rows (k-independent; gathered for K/V)
  int brow[4];
#pragma unroll
  for (int i = 0; i < 4; ++i) {
    const int r = (i * 8 + w) * 8 + (lane >> 3);
    if (kv) {
      const int t = tc[(mBase >> 11) * 2048 + (mBase & 2047) + r];
      brow[i] = (mBase & ~2047) + (t < 0 ? 0 : t);
    } else {
      brow[i] = mBase + r;
    }
  }

  auto stageA = [&](int k0, int bi, int i) {
    const int cid = (i * 8 + w) * 64 + lane;
    const int r = cid >> 3, ss = (cid & 7) ^ (r & 7);
    GLL16(A + (size_t)(oBase + r) * K + k0 + ss * 8, &At[bi][(i * 8 + w) * 512]);
  };
  auto stageB = [&](int k0, int bi, int i) {
    const int cid = (i * 8 + w) * 64 + lane;
    const int r = cid >> 3, ss = (cid & 7) ^ (r & 7);
    GLL16(Bx + (size_t)brow[i] * K + k0 + ss * 8, &Bt[bi][(i * 8 + w) * 512]);
  };
  auto rdA = [&](int bi, int of, int kc) -> bf16x8 {
    const int rr = wo + of * 16 + c;
    return *reinterpret_cast<const bf16x8*>(&At[bi][rr * 64 + (((kc * 4 + g) ^ (rr & 7)) * 8)]);
  };
  auto rdB = [&](int bi, int mf, int kc) -> bf16x8 {
    const int rr = wm + mf * 16 + c;
    return *reinterpret_cast<const bf16x8*>(&Bt[bi][rr * 64 + (((kc * 4 + g) ^ (rr & 7)) * 8)]);
  };

  f32x4 acc[4][8] = {};  // [o-frag][m-frag]

  // prologue: stage tile 0, full drain
#pragma unroll
  for (int i = 0; i < 4; ++i) { stageA(0, 0, i); stageB(0, 0, i); }
  asm volatile("s_waitcnt vmcnt(0)" ::: "memory");
  __builtin_amdgcn_s_barrier();
  __builtin_amdgcn_sched_barrier(0);

#define PHASE(mf0, STA, STB, EXTRA)                                      \
  {                                                                      \
    bf16x8 b0k0 = rdB(cur, (mf0), 0), b0k1 = rdB(cur, (mf0), 1);         \
    bf16x8 b1k0 = rdB(cur, (mf0) + 1, 0), b1k1 = rdB(cur, (mf0) + 1, 1); \
    if (more) { STA; STB; }                                              \
    __builtin_amdgcn_s_barrier();                                        \
    asm volatile("s_waitcnt lgkmcnt(0)" ::: "memory");                   \
    __builtin_amdgcn_sched_barrier(0);                                   \
    __builtin_amdgcn_s_setprio(1);                                       \
    _Pragma("unroll")                                                    \
    for (int of = 0; of < 4; ++of) {                                     \
      acc[of][(mf0)]     = mfma16(af[of][0], b0k0, acc[of][(mf0)]);      \
      acc[of][(mf0)]     = mfma16(af[of][1], b0k1, acc[of][(mf0)]);      \
      acc[of][(mf0) + 1] = mfma16(af[of][0], b1k0, acc[of][(mf0) + 1]);  \
      acc[of][(mf0) + 1] = mfma16(af[of][1], b1k1, acc[of][(mf0) + 1]);  \
    }                                                                    \
    __builtin_amdgcn_s_setprio(0);                                       \
    EXTRA;                                                               \
    __builtin_amdgcn_s_barrier();                                        \
    __builtin_amdgcn_sched_barrier(0);                                   \
  }

  for (int t = 0; t < NT; ++t) {
    const int cur = t & 1, nxt = cur ^ 1;
    const int k0n = (t + 1) * 64;
    const bool more = t < NT - 1;
    bf16x8 af[4][2];
#pragma unroll
    for (int of = 0; of < 4; ++of) {
      af[of][0] = rdA(cur, of, 0);
      af[of][1] = rdA(cur, of, 1);
    }
    PHASE(0, stageA(k0n, nxt, 0), stageB(k0n, nxt, 0), ;)
    PHASE(2, stageA(k0n, nxt, 1), stageB(k0n, nxt, 1), ;)
    PHASE(4, stageA(k0n, nxt, 2), stageB(k0n, nxt, 2), ;)
    PHASE(6, stageA(k0n, nxt, 3), stageB(k0n, nxt, 3),
          asm volatile("s_waitcnt vmcnt(0)" ::: "memory"))
  }
#undef PHASE

  // epilogue
#pragma unroll
  for (int of = 0; of < 4; ++of) {
    const int o0 = oBase + wo + of * 16 + g * 4;  // 4 consecutive o per lane
#pragma unroll
    for (int mf = 0; mf < 8; ++mf) {
      const int m = mBase + wm + mf * 16 + c;
      f32x4 v = acc[of][mf];
      if (which == 0) {  // Q
        v[0] *= SCALE_Q; v[1] *= SCALE_Q; v[2] *= SCALE_Q; v[3] *= SCALE_Q;
        bf16x4 bv;
        bv[0] = (bf16_t)v[0]; bv[1] = (bf16_t)v[1]; bv[2] = (bf16_t)v[2]; bv[3] = (bf16_t)v[3];
        const int rem = o0 & 1023;
        const int h = rem >> 6, d0 = rem & 63;
        const int b = m >> 11, t = m & 2047;
        *reinterpret_cast<bf16x4*>(qb + (((size_t)(b * 16 + h)) * 2048 + t) * 64 + d0) = bv;
      } else {
        const int i = m & 2047;  // compact key index
        if (i < nkb) {
          bf16x4 bv;
          bv[0] = (bf16_t)v[0]; bv[1] = (bf16_t)v[1]; bv[2] = (bf16_t)v[2]; bv[3] = (bf16_t)v[3];
          const int rem = o0 & 1023;
          const int h = rem >> 6, d0 = rem & 63;
          const int b = m >> 11;
          const size_t bh = (size_t)(b * 16 + h);
          if (which == 1) {
            *reinterpret_cast<bf16x4*>(kb + (bh * 2048 + i) * 64 + d0) = bv;
          } else {
#pragma unroll
            for (int jj = 0; jj < 4; ++jj)
              vtb[(bh * 64 + d0 + jj) * 2048 + i] = bv[jj];
          }
        }
      }
    }
  }
}

// ---------------- proj GEMM (R5-proven 128x128 2-phase) ----------------
__global__ __launch_bounds__(256, 2)
void gemm_proj(const bf16_t* __restrict__ A, const bf16_t* __restrict__ Bx,
               float* __restrict__ fout) {
  constexpr int K = 1024;
  __shared__ alignas(16) unsigned short At[128 * 64];
  __shared__ alignas(16) unsigned short Bt[128 * 64];
  const int tid = threadIdx.x;
  const int lane = tid & 63, w = tid >> 6;
  const int c = lane & 15, g = lane >> 4;
  const int oBase = blockIdx.x * 128, mBase = blockIdx.y * 128;
  const int wo = (w >> 1) * 64, wm = (w & 1) * 64;

  f32x4 acc[4][4] = {};

  for (int k0 = 0; k0 < K; k0 += 64) {
#pragma unroll
    for (int i = 0; i < 4; ++i) {
      const int cid = (i * 4 + w) * 64 + lane;
      const int r = cid >> 3;
      const int ss = (cid & 7) ^ (r & 7);
      GLL16(A + (size_t)(oBase + r) * K + k0 + ss * 8, &At[(i * 4 + w) * 512]);
      GLL16(Bx + (size_t)(mBase + r) * K + k0 + ss * 8, &Bt[(i * 4 + w) * 512]);
    }
    __syncthreads();
    bf16x8 af[4][2], bfr[4][2];
#pragma unroll
    for (int f = 0; f < 4; ++f) {
#pragma unroll
      for (int kc = 0; kc < 2; ++kc) {
        const int ra = wo + f * 16 + c;
        af[f][kc] = *reinterpret_cast<const bf16x8*>(&At[ra * 64 + ((kc * 4 + g) ^ (ra & 7)) * 8]);
        const int rb = wm + f * 16 + c;
        bfr[f][kc] = *reinterpret_cast<const bf16x8*>(&Bt[rb * 64 + ((kc * 4 + g) ^ (rb & 7)) * 8]);
      }
    }
    __builtin_amdgcn_s_setprio(1);
#pragma unroll
    for (int of = 0; of < 4; ++of)
#pragma unroll
      for (int mf = 0; mf < 4; ++mf)
#pragma unroll
        for (int kc = 0; kc < 2; ++kc)
          acc[of][mf] = mfma16(af[of][kc], bfr[mf][kc], acc[of][mf]);
    __builtin_amdgcn_s_setprio(0);
    __syncthreads();
  }

#pragma unroll
  for (int of = 0; of < 4; ++of) {
    const int o0 = oBase + wo + of * 16 + g * 4;
#pragma unroll
    for (int mf = 0; mf < 4; ++mf) {
      const int m = mBase + wm + mf * 16 + c;
      *reinterpret_cast<f32x4*>(fout + (size_t)m * 1024 + o0) = acc[of][mf];
    }
  }
}

// ---------------- flash attention (compacted keys, no-max raw-exp softmax) ----------------
__global__ __launch_bounds__(256, 2)
void attn_fwd(const bf16_t* __restrict__ Qg, const bf16_t* __restrict__ Kg,
              const bf16_t* __restrict__ Vtg, const int* __restrict__ nkp,
              bf16_t* __restrict__ aout) {
  constexpr int T = 2048;
  __shared__ alignas(16) unsigned short KtL[2][64 * 64];   // [k_t][d], fK-swizzled
  __shared__ alignas(16) unsigned short VtL[2][64 * 64];   // [d][k_t], fV-swizzled
  const int tid = threadIdx.x, lane = tid & 63, w = tid >> 6;
  const int c = lane & 15, g = lane >> 4;
  const int bid = blockIdx.x;
  const int xcd = bid & 7, jj = bid >> 3;
  const int bh = xcd * 8 + (jj & 7), qp = jj >> 3;  // bh [0,64), q-panel [0,8)
  const int b = bh >> 4, h = bh & 15;
  const bf16_t* Qh = Qg + (size_t)bh * T * 64;
  const bf16_t* Kh = Kg + (size_t)bh * T * 64;
  const bf16_t* Vh = Vtg + (size_t)bh * 64 * T;
  const int q0 = qp * 256 + w * 64;
  const int nkb = nkp[b];
  const int ntiles = (nkb + 63) >> 6;

  bf16x8 qfr[4][2];
#pragma unroll
  for (int qq = 0; qq < 4; ++qq)
#pragma unroll
    for (int dc = 0; dc < 2; ++dc)
      qfr[qq][dc] = *reinterpret_cast<const bf16x8*>(
          Qh + (size_t)(q0 + qq * 16 + c) * 64 + dc * 32 + g * 8);

  bf16x8 ones;
#pragma unroll
  for (int i = 0; i < 8; ++i) ones[i] = (bf16_t)1.0f;

  f32x4 oacc[4][4] = {};
  float lrun[4] = {0.f, 0.f, 0.f, 0.f};

  auto stage = [&](int t, int bi) {
    const int kt0 = t * 64;
#pragma unroll
    for (int i = 0; i < 2; ++i) {
      const int cid = (i * 4 + w) * 64 + lane;
      const int r = cid >> 3, p = cid & 7;
      const int lk = p ^ ((r & 3) | (((r >> 3) & 1) << 2));  // fK
      GLL16(Kh + (size_t)(kt0 + r) * 64 + lk * 8, &KtL[bi][(i * 4 + w) * 512]);
      const int lv = p ^ (r & 7);                            // fV
      GLL16(Vh + (size_t)r * T + kt0 + lv * 8, &VtL[bi][(i * 4 + w) * 512]);
    }
  };

  stage(0, 0);
  __syncthreads();

  const int fK = (c & 3) | (((c >> 2) & 1) << 2);

  for (int t = 0; t < ntiles; ++t) {
    const int cur = t & 1;
    if (t + 1 < ntiles) stage(t + 1, cur ^ 1);

    bf16x8 kfr[4][2];
#pragma unroll
    for (int kr = 0; kr < 4; ++kr) {
      const int row = (c >> 2) * 8 + (kr & 1) * 4 + (c & 3) + (kr >> 1) * 32;
#pragma unroll
      for (int dc = 0; dc < 2; ++dc)
        kfr[kr][dc] = *reinterpret_cast<const bf16x8*>(
            &KtL[cur][row * 64 + (((dc * 4 + g) ^ fK) * 8)]);
    }

    const bool tail = (t == ntiles - 1) && (nkb & 63) != 0;
    f32x4 bias4[4];
#pragma unroll
    for (int kr = 0; kr < 4; ++kr) {
      if (tail) {
        const int kbase = t * 64 + g * 8 + (kr & 1) * 4 + (kr >> 1) * 32;
#pragma unroll
        for (int j = 0; j < 4; ++j) bias4[kr][j] = (kbase + j < nkb) ? 0.f : -1e30f;
      } else {
        bias4[kr][0] = bias4[kr][1] = bias4[kr][2] = bias4[kr][3] = 0.f;
      }
    }

    bf16x8 pfr[4][2];
#pragma unroll
    for (int qq = 0; qq < 4; ++qq) {
      f32x4 stq[4];
      __builtin_amdgcn_s_setprio(1);
#pragma unroll
      for (int kr = 0; kr < 4; ++kr) {
        f32x4 z = mfma16(kfr[kr][0], qfr[qq][0], bias4[kr]);
        stq[kr] = mfma16(kfr[kr][1], qfr[qq][1], z);
      }
      __builtin_amdgcn_s_setprio(0);
#pragma unroll
      for (int kc = 0; kc < 2; ++kc) {
        bf16x8 p;
#pragma unroll
        for (int j = 0; j < 4; ++j) {
          p[j]     = (bf16_t)__builtin_amdgcn_exp2f(stq[kc * 2 + 0][j]);
          p[4 + j] = (bf16_t)__builtin_amdgcn_exp2f(stq[kc * 2 + 1][j]);
        }
        pfr[qq][kc] = p;
      }
      f32x4 su = {0.f, 0.f, 0.f, 0.f};
      su = mfma16(ones, pfr[qq][0], su);
      su = mfma16(ones, pfr[qq][1], su);
      lrun[qq] += su[0];
    }

    __builtin_amdgcn_s_setprio(1);
#pragma unroll
    for (int df = 0; df < 4; ++df) {
      bf16x8 va[2];
#pragma unroll
      for (int kc = 0; kc < 2; ++kc) {
        const int r = df * 16 + c;
        va[kc] = *reinterpret_cast<const bf16x8*>(
            &VtL[cur][r * 64 + ((kc * 4 + g) ^ (r & 7)) * 8]);
      }
#pragma unroll
      for (int qq = 0; qq < 4; ++qq)
#pragma unroll
        for (int kc = 0; kc < 2; ++kc)
          oacc[df][qq] = mfma16(va[kc], pfr[qq][kc], oacc[df][qq]);
    }
    __builtin_amdgcn_s_setprio(0);
    __syncthreads();
  }

#pragma unroll
  for (int qq = 0; qq < 4; ++qq) {
    const float inv = 1.0f / lrun[qq];
    const int q = q0 + qq * 16 + c;
#pragma unroll
    for (int df = 0; df < 4; ++df) {
      bf16x4 bv;
#pragma unroll
      for (int j = 0; j < 4; ++j) bv[j] = (bf16_t)(oacc[df][qq][j] * inv);
      const int d0 = df * 16 + g * 4;
      *reinterpret_cast<bf16x4*>(aout + ((size_t)(b * 2048 + q)) * 1024 + h * 64 + d0) = bv;
    }
  }
}

// ---------------- launch ----------------
extern "C" void kernel_launch(void* const* d_in, const int* in_sizes, int n_in,
                              void* d_out, int out_size, void* d_ws, size_t ws_size,
                              hipStream_t stream) {
  (void)in_sizes; (void)n_in; (void)out_size; (void)ws_size;
  const float* x = (const float*)d_in[0];
  const int* pmask = (const int*)d_in[1];
  const float* wqkv = (const float*)d_in[2];
  const float* wproj = (const float*)d_in[3];
  float* out = (float*)d_out;
  char* ws = (char*)d_ws;

  bf16_t* xb    = (bf16_t*)(ws + 0);          // 16 MiB  [8192][1024]
  bf16_t* aob   = (bf16_t*)(ws + 0);          // overlay: attn out after x is dead
  bf16_t* wqkvb = (bf16_t*)(ws + 16777216);   // 6 MiB   [3072][1024]
  bf16_t* wprojb= (bf16_t*)(ws + 23068672);   // 2 MiB   [1024][1024]
  bf16_t* Qb    = (bf16_t*)(ws + 25165824);   // 16 MiB  [64][2048][64]
  bf16_t* Kb    = (bf16_t*)(ws + 41943040);   // 16 MiB  (compacted rows)
  bf16_t* Vtb   = (bf16_t*)(ws + 58720256);   // 16 MiB  [64][64][2048]

  int* tc  = (int*)d_out;            // 4*2048 ints (scratch in d_out)
  int* nkp = tc + 4 * 2048;          // 4 ints

  prep<<<12292, 256, 0, stream>>>(x, wqkv, wproj, xb, wqkvb, wprojb,
                                  pmask, tc, nkp, Kb, Vtb);

  gemm_qkv8<<<384, 512, 0, stream>>>(wqkvb, xb, Qb, Kb, Vtb, tc, nkp);
  attn_fwd<<<512, 256, 0, stream>>>(Qb, Kb, Vtb, nkp, aob);
  gemm_proj<<<dim3(8, 64), 256, 0, stream>>>(wprojb, aob, out);
}

// Round 11
// 165.948 us; speedup vs baseline: 1.0262x; 1.0262x over previous
//
#include <hip/hip_runtime.h>
#include <hip/hip_bf16.h>
#include <stdint.h>

typedef __bf16 bf16_t;
typedef __bf16 bf16x8 __attribute__((ext_vector_type(8)));
typedef __bf16 bf16x4 __attribute__((ext_vector_type(4)));
typedef float f32x4 __attribute__((ext_vector_type(4)));

#define DEVFN static __device__ __forceinline__

DEVFN f32x4 mfma16(bf16x8 a, bf16x8 b, f32x4 c) {
  return __builtin_amdgcn_mfma_f32_16x16x32_bf16(a, b, c, 0, 0, 0);
}

// global -> LDS direct copy, 16B per lane; LDS dest must be wave-uniform.
#define GLL16(gsrc, ldst) __builtin_amdgcn_global_load_lds( \
    (__attribute__((address_space(1))) void*)(gsrc), \
    (__attribute__((address_space(3))) void*)(ldst), 16, 0, 0)

// softmax scale * log2(e), folded into Q at the QKV-GEMM epilogue
#define SCALE_Q 0.1803368801111204f

// ---------------- prep: fp32->bf16 conversion + key compaction (merged) ----------------
__global__ void prep(const float* __restrict__ x, const float* __restrict__ wqkv,
                     const float* __restrict__ wproj, bf16_t* __restrict__ xb,
                     bf16_t* __restrict__ wqkvb, bf16_t* __restrict__ wprojb,
                     const int* __restrict__ mask, int* __restrict__ tc,
                     int* __restrict__ nk, bf16_t* __restrict__ kb,
                     bf16_t* __restrict__ vtb) {
  const int tid = threadIdx.x;
  if (blockIdx.x < 12288) {
    const int i = blockIdx.x * 256 + tid;
    const float* s;
    bf16_t* d;
    int off;
    if (i < 2097152) { s = x; d = xb; off = i; }
    else if (i < 2097152 + 786432) { s = wqkv; d = wqkvb; off = i - 2097152; }
    else { s = wproj; d = wprojb; off = i - 2883584; }
    f32x4 v = reinterpret_cast<const f32x4*>(s)[off];
    bf16x4 o;
    o[0] = (bf16_t)v[0]; o[1] = (bf16_t)v[1]; o[2] = (bf16_t)v[2]; o[3] = (bf16_t)v[3];
    reinterpret_cast<bf16x4*>(d)[off] = o;
    return;
  }
  // ---- compaction ----
  const int b = blockIdx.x - 12288;
  const int lane = tid & 63, wv = tid >> 6;
  __shared__ int nk_s;
  const int* mrow = mask + b * 2048;
  if (wv == 0) {
    int base = 0;
    for (int cs = 0; cs < 2048; cs += 64) {
      const int mval = mrow[cs + lane];
      const unsigned long long bal = __ballot(mval == 0);
      const int pre = __popcll(bal & ((1ull << lane) - 1ull));
      if (!mval) tc[b * 2048 + base + pre] = cs + lane;
      base += __popcll(bal);
    }
    if (lane == 0) nk_s = base;
  }
  __syncthreads();
  const int nkb = nk_s;
  if (tid == 0) nk[b] = nkb;
  for (int i = nkb + tid; i < 2048; i += 256) tc[b * 2048 + i] = -1;
  const int ce = (nkb + 63) & ~63;
  for (int hh = wv; hh < 16; hh += 4) {
    const size_t bh = (size_t)(b * 16 + hh);
    for (int r = nkb; r < ce; ++r) {
      kb[(bh * 2048 + r) * 64 + lane] = (bf16_t)0.f;
      vtb[(bh * 64 + lane) * 2048 + r] = (bf16_t)0.f;
    }
  }
}

// ---------------- QKV GEMM: 3-buffer 2-tile-ahead counted-vmcnt (T3+T4) ----------------
// C^T = W[O][K] * x[M][K]^T. Block = 128(o) x 256(m), 512 thr / 8 waves
// (wave: 64o x 64m). LDS 144KB = 3 x (A 16KB + B 32KB). During tile t we
// issue tile t+2's 6 global_load_lds; at tile t close, vmcnt(6) retires
// exactly tile t+1's 6 loads (issued a full tile earlier -> wait ~free).
// 2 phases per K-tile: {12 ds_read ; 3 GLL ; bar ; lgkmcnt0 ; 16 MFMA ; bar}
// then {4 ds_read ; 3 GLL ; bar ; lgkmcnt0 ; 16 MFMA ; vmcnt(6) ; bar}.
// Grid 768 = 24 bx * 32 my (natural order: pad-exit blocks spread over XCDs).
// bx<8: Q (scaled); 8-15: K; 16-23: V (compacted via tc).
__global__ __launch_bounds__(512, 1)
void gemm_qkv3(const bf16_t* __restrict__ A, const bf16_t* __restrict__ Bx,
               bf16_t* __restrict__ qb, bf16_t* __restrict__ kb,
               bf16_t* __restrict__ vtb,
               const int* __restrict__ tc, const int* __restrict__ nkp) {
  constexpr int K = 1024;
  constexpr int NT = 16;  // K-tiles of 64
  __shared__ alignas(16) unsigned short At[3][128 * 64];   // 48 KB
  __shared__ alignas(16) unsigned short Bt[3][256 * 64];   // 96 KB
  const int tid = threadIdx.x, lane = tid & 63, w = tid >> 6;
  const int c = lane & 15, g = lane >> 4;
  const int bid = blockIdx.x;
  const int bx = bid % 24, my = bid / 24;
  const int oBase = bx * 128, mBase = my * 256;
  const int wo = (w & 1) * 64, wm = (w >> 1) * 64;
  const int which = bx >> 3;                        // 0=Q 1=K 2=V
  const bool kv = which != 0;
  const int nkb = nkp[mBase >> 11];
  if (kv && (mBase & 2047) >= nkb) return;          // whole tile is pad (uniform)

  // per-lane B source rows (k-independent; gathered for K/V)
  int brow[4];
#pragma unroll
  for (int i = 0; i < 4; ++i) {
    const int r = (i * 8 + w) * 8 + (lane >> 3);
    if (kv) {
      const int t = tc[(mBase >> 11) * 2048 + (mBase & 2047) + r];
      brow[i] = (mBase & ~2047) + (t < 0 ? 0 : t);
    } else {
      brow[i] = mBase + r;
    }
  }

  auto stageA = [&](int k0, int bi, int i) {   // i in {0,1}
    const int cid = (i * 8 + w) * 64 + lane;
    const int r = cid >> 3, ss = (cid & 7) ^ (r & 7);
    GLL16(A + (size_t)(oBase + r) * K + k0 + ss * 8, &At[bi][(i * 8 + w) * 512]);
  };
  auto stageB = [&](int k0, int bi, int i) {   // i in {0..3}
    const int cid = (i * 8 + w) * 64 + lane;
    const int r = cid >> 3, ss = (cid & 7) ^ (r & 7);
    GLL16(Bx + (size_t)brow[i] * K + k0 + ss * 8, &Bt[bi][(i * 8 + w) * 512]);
  };
  auto rdA = [&](int bi, int of, int kc) -> bf16x8 {
    const int rr = wo + of * 16 + c;
    return *reinterpret_cast<const bf16x8*>(&At[bi][rr * 64 + (((kc * 4 + g) ^ (rr & 7)) * 8)]);
  };
  auto rdB = [&](int bi, int mf, int kc) -> bf16x8 {
    const int rr = wm + mf * 16 + c;
    return *reinterpret_cast<const bf16x8*>(&Bt[bi][rr * 64 + (((kc * 4 + g) ^ (rr & 7)) * 8)]);
  };

  f32x4 acc[4][4] = {};  // [o-frag][m-frag]

  // prologue: stage tiles 0 and 1; wait tile 0 (own outstanding 12 -> <=6)
#pragma unroll
  for (int i = 0; i < 2; ++i) stageA(0, 0, i);
#pragma unroll
  for (int i = 0; i < 4; ++i) stageB(0, 0, i);
#pragma unroll
  for (int i = 0; i < 2; ++i) stageA(64, 1, i);
#pragma unroll
  for (int i = 0; i < 4; ++i) stageB(64, 1, i);
  asm volatile("s_waitcnt vmcnt(6)" ::: "memory");
  __builtin_amdgcn_s_barrier();
  __builtin_amdgcn_sched_barrier(0);

  int bi = 0;
  for (int t = 0; t < NT; ++t) {
    const int bi2 = (t + 2 < 3) ? (t + 2) : ((t + 2) % 3);
    const int k2 = (t + 2) * 64;
    const bool more2 = (t + 2) < NT;

    // ---- phase 1: A frags + B frags(mf 0,1) ; stage A(2) + B(1 of next+2)
    bf16x8 af[4][2];
#pragma unroll
    for (int of = 0; of < 4; ++of) {
      af[of][0] = rdA(bi, of, 0);
      af[of][1] = rdA(bi, of, 1);
    }
    bf16x8 b00 = rdB(bi, 0, 0), b01 = rdB(bi, 0, 1);
    bf16x8 b10 = rdB(bi, 1, 0), b11 = rdB(bi, 1, 1);
    if (more2) { stageA(k2, bi2, 0); stageA(k2, bi2, 1); stageB(k2, bi2, 0); }
    __builtin_amdgcn_s_barrier();
    asm volatile("s_waitcnt lgkmcnt(0)" ::: "memory");
    __builtin_amdgcn_sched_barrier(0);
    __builtin_amdgcn_s_setprio(1);
#pragma unroll
    for (int of = 0; of < 4; ++of) {
      acc[of][0] = mfma16(af[of][0], b00, acc[of][0]);
      acc[of][0] = mfma16(af[of][1], b01, acc[of][0]);
      acc[of][1] = mfma16(af[of][0], b10, acc[of][1]);
      acc[of][1] = mfma16(af[of][1], b11, acc[of][1]);
    }
    __builtin_amdgcn_s_setprio(0);
    __builtin_amdgcn_s_barrier();
    __builtin_amdgcn_sched_barrier(0);

    // ---- phase 2: B frags(mf 2,3) ; stage B(remaining 3)
    bf16x8 b20 = rdB(bi, 2, 0), b21 = rdB(bi, 2, 1);
    bf16x8 b30 = rdB(bi, 3, 0), b31 = rdB(bi, 3, 1);
    if (more2) { stageB(k2, bi2, 1); stageB(k2, bi2, 2); stageB(k2, bi2, 3); }
    __builtin_amdgcn_s_barrier();
    asm volatile("s_waitcnt lgkmcnt(0)" ::: "memory");
    __builtin_amdgcn_sched_barrier(0);
    __builtin_amdgcn_s_setprio(1);
#pragma unroll
    for (int of = 0; of < 4; ++of) {
      acc[of][2] = mfma16(af[of][0], b20, acc[of][2]);
      acc[of][2] = mfma16(af[of][1], b21, acc[of][2]);
      acc[of][3] = mfma16(af[of][0], b30, acc[of][3]);
      acc[of][3] = mfma16(af[of][1], b31, acc[of][3]);
    }
    __builtin_amdgcn_s_setprio(0);
    // counted wait: retire tile t+1's loads (issued a full tile ago)
    if (t < NT - 2) {
      asm volatile("s_waitcnt vmcnt(6)" ::: "memory");
    } else if (t == NT - 2) {
      asm volatile("s_waitcnt vmcnt(0)" ::: "memory");
    }
    __builtin_amdgcn_s_barrier();
    __builtin_amdgcn_sched_barrier(0);

    bi = (bi == 2) ? 0 : bi + 1;
  }

  // epilogue
#pragma unroll
  for (int of = 0; of < 4; ++of) {
    const int o0 = oBase + wo + of * 16 + g * 4;  // 4 consecutive o per lane
#pragma unroll
    for (int mf = 0; mf < 4; ++mf) {
      const int m = mBase + wm + mf * 16 + c;
      f32x4 v = acc[of][mf];
      if (which == 0) {  // Q
        v[0] *= SCALE_Q; v[1] *= SCALE_Q; v[2] *= SCALE_Q; v[3] *= SCALE_Q;
        bf16x4 bv;
        bv[0] = (bf16_t)v[0]; bv[1] = (bf16_t)v[1]; bv[2] = (bf16_t)v[2]; bv[3] = (bf16_t)v[3];
        const int rem = o0 & 1023;
        const int h = rem >> 6, d0 = rem & 63;
        const int b = m >> 11, t = m & 2047;
        *reinterpret_cast<bf16x4*>(qb + (((size_t)(b * 16 + h)) * 2048 + t) * 64 + d0) = bv;
      } else {
        const int i = m & 2047;  // compact key index
        if (i < nkb) {
          bf16x4 bv;
          bv[0] = (bf16_t)v[0]; bv[1] = (bf16_t)v[1]; bv[2] = (bf16_t)v[2]; bv[3] = (bf16_t)v[3];
          const int rem = o0 & 1023;
          const int h = rem >> 6, d0 = rem & 63;
          const int b = m >> 11;
          const size_t bh = (size_t)(b * 16 + h);
          if (which == 1) {
            *reinterpret_cast<bf16x4*>(kb + (bh * 2048 + i) * 64 + d0) = bv;
          } else {
#pragma unroll
            for (int jj = 0; jj < 4; ++jj)
              vtb[(bh * 64 + d0 + jj) * 2048 + i] = bv[jj];
          }
        }
      }
    }
  }
}

// ---------------- proj GEMM (R5-proven 128x128 2-phase) ----------------
__global__ __launch_bounds__(256, 2)
void gemm_proj(const bf16_t* __restrict__ A, const bf16_t* __restrict__ Bx,
               float* __restrict__ fout) {
  constexpr int K = 1024;
  __shared__ alignas(16) unsigned short At[128 * 64];
  __shared__ alignas(16) unsigned short Bt[128 * 64];
  const int tid = threadIdx.x;
  const int lane = tid & 63, w = tid >> 6;
  const int c = lane & 15, g = lane >> 4;
  const int oBase = blockIdx.x * 128, mBase = blockIdx.y * 128;
  const int wo = (w >> 1) * 64, wm = (w & 1) * 64;

  f32x4 acc[4][4] = {};

  for (int k0 = 0; k0 < K; k0 += 64) {
#pragma unroll
    for (int i = 0; i < 4; ++i) {
      const int cid = (i * 4 + w) * 64 + lane;
      const int r = cid >> 3;
      const int ss = (cid & 7) ^ (r & 7);
      GLL16(A + (size_t)(oBase + r) * K + k0 + ss * 8, &At[(i * 4 + w) * 512]);
      GLL16(Bx + (size_t)(mBase + r) * K + k0 + ss * 8, &Bt[(i * 4 + w) * 512]);
    }
    __syncthreads();
    bf16x8 af[4][2], bfr[4][2];
#pragma unroll
    for (int f = 0; f < 4; ++f) {
#pragma unroll
      for (int kc = 0; kc < 2; ++kc) {
        const int ra = wo + f * 16 + c;
        af[f][kc] = *reinterpret_cast<const bf16x8*>(&At[ra * 64 + ((kc * 4 + g) ^ (ra & 7)) * 8]);
        const int rb = wm + f * 16 + c;
        bfr[f][kc] = *reinterpret_cast<const bf16x8*>(&Bt[rb * 64 + ((kc * 4 + g) ^ (rb & 7)) * 8]);
      }
    }
    __builtin_amdgcn_s_setprio(1);
#pragma unroll
    for (int of = 0; of < 4; ++of)
#pragma unroll
      for (int mf = 0; mf < 4; ++mf)
#pragma unroll
        for (int kc = 0; kc < 2; ++kc)
          acc[of][mf] = mfma16(af[of][kc], bfr[mf][kc], acc[of][mf]);
    __builtin_amdgcn_s_setprio(0);
    __syncthreads();
  }

#pragma unroll
  for (int of = 0; of < 4; ++of) {
    const int o0 = oBase + wo + of * 16 + g * 4;
#pragma unroll
    for (int mf = 0; mf < 4; ++mf) {
      const int m = mBase + wm + mf * 16 + c;
      *reinterpret_cast<f32x4*>(fout + (size_t)m * 1024 + o0) = acc[of][mf];
    }
  }
}

// ---------------- flash attention (compacted keys, no-max raw-exp softmax) ----------------
__global__ __launch_bounds__(256, 2)
void attn_fwd(const bf16_t* __restrict__ Qg, const bf16_t* __restrict__ Kg,
              const bf16_t* __restrict__ Vtg, const int* __restrict__ nkp,
              bf16_t* __restrict__ aout) {
  constexpr int T = 2048;
  __shared__ alignas(16) unsigned short KtL[2][64 * 64];   // [k_t][d], fK-swizzled
  __shared__ alignas(16) unsigned short VtL[2][64 * 64];   // [d][k_t], fV-swizzled
  const int tid = threadIdx.x, lane = tid & 63, w = tid >> 6;
  const int c = lane & 15, g = lane >> 4;
  const int bid = blockIdx.x;
  const int xcd = bid & 7, jj = bid >> 3;
  const int bh = xcd * 8 + (jj & 7), qp = jj >> 3;  // bh [0,64), q-panel [0,8)
  const int b = bh >> 4, h = bh & 15;
  const bf16_t* Qh = Qg + (size_t)bh * T * 64;
  const bf16_t* Kh = Kg + (size_t)bh * T * 64;
  const bf16_t* Vh = Vtg + (size_t)bh * 64 * T;
  const int q0 = qp * 256 + w * 64;
  const int nkb = nkp[b];
  const int ntiles = (nkb + 63) >> 6;

  bf16x8 qfr[4][2];
#pragma unroll
  for (int qq = 0; qq < 4; ++qq)
#pragma unroll
    for (int dc = 0; dc < 2; ++dc)
      qfr[qq][dc] = *reinterpret_cast<const bf16x8*>(
          Qh + (size_t)(q0 + qq * 16 + c) * 64 + dc * 32 + g * 8);

  bf16x8 ones;
#pragma unroll
  for (int i = 0; i < 8; ++i) ones[i] = (bf16_t)1.0f;

  f32x4 oacc[4][4] = {};
  float lrun[4] = {0.f, 0.f, 0.f, 0.f};

  auto stage = [&](int t, int bi) {
    const int kt0 = t * 64;
#pragma unroll
    for (int i = 0; i < 2; ++i) {
      const int cid = (i * 4 + w) * 64 + lane;
      const int r = cid >> 3, p = cid & 7;
      const int lk = p ^ ((r & 3) | (((r >> 3) & 1) << 2));  // fK
      GLL16(Kh + (size_t)(kt0 + r) * 64 + lk * 8, &KtL[bi][(i * 4 + w) * 512]);
      const int lv = p ^ (r & 7);                            // fV
      GLL16(Vh + (size_t)r * T + kt0 + lv * 8, &VtL[bi][(i * 4 + w) * 512]);
    }
  };

  stage(0, 0);
  __syncthreads();

  const int fK = (c & 3) | (((c >> 2) & 1) << 2);

  for (int t = 0; t < ntiles; ++t) {
    const int cur = t & 1;
    if (t + 1 < ntiles) stage(t + 1, cur ^ 1);

    bf16x8 kfr[4][2];
#pragma unroll
    for (int kr = 0; kr < 4; ++kr) {
      const int row = (c >> 2) * 8 + (kr & 1) * 4 + (c & 3) + (kr >> 1) * 32;
#pragma unroll
      for (int dc = 0; dc < 2; ++dc)
        kfr[kr][dc] = *reinterpret_cast<const bf16x8*>(
            &KtL[cur][row * 64 + (((dc * 4 + g) ^ fK) * 8)]);
    }

    const bool tail = (t == ntiles - 1) && (nkb & 63) != 0;
    f32x4 bias4[4];
#pragma unroll
    for (int kr = 0; kr < 4; ++kr) {
      if (tail) {
        const int kbase = t * 64 + g * 8 + (kr & 1) * 4 + (kr >> 1) * 32;
#pragma unroll
        for (int j = 0; j < 4; ++j) bias4[kr][j] = (kbase + j < nkb) ? 0.f : -1e30f;
      } else {
        bias4[kr][0] = bias4[kr][1] = bias4[kr][2] = bias4[kr][3] = 0.f;
      }
    }

    bf16x8 pfr[4][2];
#pragma unroll
    for (int qq = 0; qq < 4; ++qq) {
      f32x4 stq[4];
      __builtin_amdgcn_s_setprio(1);
#pragma unroll
      for (int kr = 0; kr < 4; ++kr) {
        f32x4 z = mfma16(kfr[kr][0], qfr[qq][0], bias4[kr]);
        stq[kr] = mfma16(kfr[kr][1], qfr[qq][1], z);
      }
      __builtin_amdgcn_s_setprio(0);
#pragma unroll
      for (int kc = 0; kc < 2; ++kc) {
        bf16x8 p;
#pragma unroll
        for (int j = 0; j < 4; ++j) {
          p[j]     = (bf16_t)__builtin_amdgcn_exp2f(stq[kc * 2 + 0][j]);
          p[4 + j] = (bf16_t)__builtin_amdgcn_exp2f(stq[kc * 2 + 1][j]);
        }
        pfr[qq][kc] = p;
      }
      f32x4 su = {0.f, 0.f, 0.f, 0.f};
      su = mfma16(ones, pfr[qq][0], su);
      su = mfma16(ones, pfr[qq][1], su);
      lrun[qq] += su[0];
    }

    __builtin_amdgcn_s_setprio(1);
#pragma unroll
    for (int df = 0; df < 4; ++df) {
      bf16x8 va[2];
#pragma unroll
      for (int kc = 0; kc < 2; ++kc) {
        const int r = df * 16 + c;
        va[kc] = *reinterpret_cast<const bf16x8*>(
            &VtL[cur][r * 64 + ((kc * 4 + g) ^ (r & 7)) * 8]);
      }
#pragma unroll
      for (int qq = 0; qq < 4; ++qq)
#pragma unroll
        for (int kc = 0; kc < 2; ++kc)
          oacc[df][qq] = mfma16(va[kc], pfr[qq][kc], oacc[df][qq]);
    }
    __builtin_amdgcn_s_setprio(0);
    __syncthreads();
  }

#pragma unroll
  for (int qq = 0; qq < 4; ++qq) {
    const float inv = 1.0f / lrun[qq];
    const int q = q0 + qq * 16 + c;
#pragma unroll
    for (int df = 0; df < 4; ++df) {
      bf16x4 bv;
#pragma unroll
      for (int j = 0; j < 4; ++j) bv[j] = (bf16_t)(oacc[df][qq][j] * inv);
      const int d0 = df * 16 + g * 4;
      *reinterpret_cast<bf16x4*>(aout + ((size_t)(b * 2048 + q)) * 1024 + h * 64 + d0) = bv;
    }
  }
}

// ---------------- launch ----------------
extern "C" void kernel_launch(void* const* d_in, const int* in_sizes, int n_in,
                              void* d_out, int out_size, void* d_ws, size_t ws_size,
                              hipStream_t stream) {
  (void)in_sizes; (void)n_in; (void)out_size; (void)ws_size;
  const float* x = (const float*)d_in[0];
  const int* pmask = (const int*)d_in[1];
  const float* wqkv = (const float*)d_in[2];
  const float* wproj = (const float*)d_in[3];
  float* out = (float*)d_out;
  char* ws = (char*)d_ws;

  bf16_t* xb    = (bf16_t*)(ws + 0);          // 16 MiB  [8192][1024]
  bf16_t* aob   = (bf16_t*)(ws + 0);          // overlay: attn out after x is dead
  bf16_t* wqkvb = (bf16_t*)(ws + 16777216);   // 6 MiB   [3072][1024]
  bf16_t* wprojb= (bf16_t*)(ws + 23068672);   // 2 MiB   [1024][1024]
  bf16_t* Qb    = (bf16_t*)(ws + 25165824);   // 16 MiB  [64][2048][64]
  bf16_t* Kb    = (bf16_t*)(ws + 41943040);   // 16 MiB  (compacted rows)
  bf16_t* Vtb   = (bf16_t*)(ws + 58720256);   // 16 MiB  [64][64][2048]

  int* tc  = (int*)d_out;            // 4*2048 ints (scratch in d_out)
  int* nkp = tc + 4 * 2048;          // 4 ints

  prep<<<12292, 256, 0, stream>>>(x, wqkv, wproj, xb, wqkvb, wprojb,
                                  pmask, tc, nkp, Kb, Vtb);

  gemm_qkv3<<<768, 512, 0, stream>>>(wqkvb, xb, Qb, Kb, Vtb, tc, nkp);
  attn_fwd<<<512, 256, 0, stream>>>(Qb, Kb, Vtb, nkp, aob);
  gemm_proj<<<dim3(8, 64), 256, 0, stream>>>(wprojb, aob, out);
}

// Round 12
// 159.426 us; speedup vs baseline: 1.0682x; 1.0409x over previous
//
#include <hip/hip_runtime.h>
#include <hip/hip_bf16.h>
#include <stdint.h>

typedef __bf16 bf16_t;
typedef __bf16 bf16x8 __attribute__((ext_vector_type(8)));
typedef __bf16 bf16x4 __attribute__((ext_vector_type(4)));
typedef float f32x4 __attribute__((ext_vector_type(4)));

#define DEVFN static __device__ __forceinline__

DEVFN f32x4 mfma16(bf16x8 a, bf16x8 b, f32x4 c) {
  return __builtin_amdgcn_mfma_f32_16x16x32_bf16(a, b, c, 0, 0, 0);
}

// global -> LDS direct copy, 16B per lane; LDS dest must be wave-uniform.
#define GLL16(gsrc, ldst) __builtin_amdgcn_global_load_lds( \
    (__attribute__((address_space(1))) void*)(gsrc), \
    (__attribute__((address_space(3))) void*)(ldst), 16, 0, 0)

// softmax scale * log2(e), folded into Q at the QKV-GEMM epilogue
#define SCALE_Q 0.1803368801111204f

// ---------------- prep: fp32->bf16 conversion + key compaction (merged) ----------------
__global__ void prep(const float* __restrict__ x, const float* __restrict__ wqkv,
                     const float* __restrict__ wproj, bf16_t* __restrict__ xb,
                     bf16_t* __restrict__ wqkvb, bf16_t* __restrict__ wprojb,
                     const int* __restrict__ mask, int* __restrict__ tc,
                     int* __restrict__ nk, bf16_t* __restrict__ kb,
                     bf16_t* __restrict__ vtb) {
  const int tid = threadIdx.x;
  if (blockIdx.x < 12288) {
    const int i = blockIdx.x * 256 + tid;
    const float* s;
    bf16_t* d;
    int off;
    if (i < 2097152) { s = x; d = xb; off = i; }
    else if (i < 2097152 + 786432) { s = wqkv; d = wqkvb; off = i - 2097152; }
    else { s = wproj; d = wprojb; off = i - 2883584; }
    f32x4 v = reinterpret_cast<const f32x4*>(s)[off];
    bf16x4 o;
    o[0] = (bf16_t)v[0]; o[1] = (bf16_t)v[1]; o[2] = (bf16_t)v[2]; o[3] = (bf16_t)v[3];
    reinterpret_cast<bf16x4*>(d)[off] = o;
    return;
  }
  // ---- compaction ----
  const int b = blockIdx.x - 12288;
  const int lane = tid & 63, wv = tid >> 6;
  __shared__ int nk_s;
  const int* mrow = mask + b * 2048;
  if (wv == 0) {
    int base = 0;
    for (int cs = 0; cs < 2048; cs += 64) {
      const int mval = mrow[cs + lane];
      const unsigned long long bal = __ballot(mval == 0);
      const int pre = __popcll(bal & ((1ull << lane) - 1ull));
      if (!mval) tc[b * 2048 + base + pre] = cs + lane;
      base += __popcll(bal);
    }
    if (lane == 0) nk_s = base;
  }
  __syncthreads();
  const int nkb = nk_s;
  if (tid == 0) nk[b] = nkb;
  for (int i = nkb + tid; i < 2048; i += 256) tc[b * 2048 + i] = -1;
  const int ce = (nkb + 63) & ~63;
  for (int hh = wv; hh < 16; hh += 4) {
    const size_t bh = (size_t)(b * 16 + hh);
    for (int r = nkb; r < ce; ++r) {
      kb[(bh * 2048 + r) * 64 + lane] = (bf16_t)0.f;
      vtb[(bh * 64 + lane) * 2048 + r] = (bf16_t)0.f;
    }
  }
}

// ---------------- GEMM: C^T = A(W[O][K]) * B(x[M][K])^T ----------------
// R5-proven config: 128x128 tile, single-buffered, 32KB LDS, ~5 blocks/CU.
// EPI 0: QKV (grid 24x64). Q blocks (bx<8) dense; K/V blocks (bx>=8) gather
//        B-rows via tc (compacted keys), store K[BH][i][64] / Vt[BH][64][i].
// EPI 1: proj (grid 8x64), fp32 row-major out [M][1024].
template <int EPI>
__global__ __launch_bounds__(256, 2)
void gemm_ct(const bf16_t* __restrict__ A, const bf16_t* __restrict__ Bx,
             bf16_t* __restrict__ qb, bf16_t* __restrict__ kb,
             bf16_t* __restrict__ vtb, float* __restrict__ fout,
             const int* __restrict__ tc, const int* __restrict__ nkp) {
  constexpr int K = 1024;
  __shared__ alignas(16) unsigned short At[128 * 64];
  __shared__ alignas(16) unsigned short Bt[128 * 64];
  const int tid = threadIdx.x;
  const int lane = tid & 63, w = tid >> 6;
  const int c = lane & 15, g = lane >> 4;
  const int oBase = blockIdx.x * 128, mBase = blockIdx.y * 128;
  const int wo = (w >> 1) * 64, wm = (w & 1) * 64;

  int nkb = 0;
  bool kv = false;
  if (EPI == 0) {
    nkb = nkp[mBase >> 11];
    kv = (blockIdx.x >= 8);
    if (kv && (mBase & 2047) >= nkb) return;  // whole block is pad (uniform)
  }
  // per-lane B source rows (k-independent; gathered for K/V blocks)
  int brow[4];
#pragma unroll
  for (int i = 0; i < 4; ++i) {
    const int r = (i * 4 + w) * 8 + (lane >> 3);
    if (EPI == 0 && kv) {
      const int t = tc[(mBase >> 11) * 2048 + (mBase & 2047) + r];
      brow[i] = (mBase & ~2047) + (t < 0 ? 0 : t);
    } else {
      brow[i] = mBase + r;
    }
  }

  f32x4 acc[4][4] = {};

  for (int k0 = 0; k0 < K; k0 += 64) {
#pragma unroll
    for (int i = 0; i < 4; ++i) {
      const int cid = (i * 4 + w) * 64 + lane;
      const int r = cid >> 3;
      const int ss = (cid & 7) ^ (r & 7);  // pre-swizzled global source slot
      GLL16(A + (size_t)(oBase + r) * K + k0 + ss * 8, &At[(i * 4 + w) * 512]);
      GLL16(Bx + (size_t)brow[i] * K + k0 + ss * 8, &Bt[(i * 4 + w) * 512]);
    }
    __syncthreads();
    bf16x8 af[4][2], bfr[4][2];
#pragma unroll
    for (int f = 0; f < 4; ++f) {
#pragma unroll
      for (int kc = 0; kc < 2; ++kc) {
        const int ra = wo + f * 16 + c;
        af[f][kc] = *reinterpret_cast<const bf16x8*>(&At[ra * 64 + ((kc * 4 + g) ^ (ra & 7)) * 8]);
        const int rb = wm + f * 16 + c;
        bfr[f][kc] = *reinterpret_cast<const bf16x8*>(&Bt[rb * 64 + ((kc * 4 + g) ^ (rb & 7)) * 8]);
      }
    }
    __builtin_amdgcn_s_setprio(1);
#pragma unroll
    for (int of = 0; of < 4; ++of)
#pragma unroll
      for (int mf = 0; mf < 4; ++mf)
#pragma unroll
        for (int kc = 0; kc < 2; ++kc)
          acc[of][mf] = mfma16(af[of][kc], bfr[mf][kc], acc[of][mf]);
    __builtin_amdgcn_s_setprio(0);
    __syncthreads();
  }

#pragma unroll
  for (int of = 0; of < 4; ++of) {
    const int o0 = oBase + wo + of * 16 + g * 4;  // 4 consecutive o per lane
#pragma unroll
    for (int mf = 0; mf < 4; ++mf) {
      const int m = mBase + wm + mf * 16 + c;
      f32x4 v = acc[of][mf];
      if (EPI == 0) {
        if (!kv) {  // Q
          v[0] *= SCALE_Q; v[1] *= SCALE_Q; v[2] *= SCALE_Q; v[3] *= SCALE_Q;
          bf16x4 bv;
          bv[0] = (bf16_t)v[0]; bv[1] = (bf16_t)v[1]; bv[2] = (bf16_t)v[2]; bv[3] = (bf16_t)v[3];
          const int rem = o0 & 1023;
          const int h = rem >> 6, d0 = rem & 63;
          const int b = m >> 11, t = m & 2047;
          *reinterpret_cast<bf16x4*>(qb + (((size_t)(b * 16 + h)) * 2048 + t) * 64 + d0) = bv;
        } else {
          const int i = m & 2047;  // compact key index
          if (i < nkb) {
            bf16x4 bv;
            bv[0] = (bf16_t)v[0]; bv[1] = (bf16_t)v[1]; bv[2] = (bf16_t)v[2]; bv[3] = (bf16_t)v[3];
            const int rem = o0 & 1023;
            const int h = rem >> 6, d0 = rem & 63;
            const int b = m >> 11;
            const size_t bh = (size_t)(b * 16 + h);
            if (blockIdx.x < 16) {
              *reinterpret_cast<bf16x4*>(kb + (bh * 2048 + i) * 64 + d0) = bv;
            } else {
#pragma unroll
              for (int j = 0; j < 4; ++j)
                vtb[(bh * 64 + d0 + j) * 2048 + i] = bv[j];
            }
          }
        }
      } else {
        *reinterpret_cast<f32x4*>(fout + (size_t)m * 1024 + o0) = v;
      }
    }
  }
}

// ---------------- flash attention (compacted keys, no-max raw-exp softmax) ----------------
// Q (pre-scaled): [BH][T][64] ; K: [BH][i][64] ; Vt: [BH][64][i].
// 8 waves/block, 64 q-rows/wave (512 q per block). Grid 256 = exactly
// 1 block/CU (zero quantization); K/V staged 4x per bh (was 8x).
// XCD-aware: the 4 q-panels of one bh land on one XCD (K/V stays in its L2).
__global__ __launch_bounds__(512, 1)
void attn_fwd(const bf16_t* __restrict__ Qg, const bf16_t* __restrict__ Kg,
              const bf16_t* __restrict__ Vtg, const int* __restrict__ nkp,
              bf16_t* __restrict__ aout) {
  constexpr int T = 2048;
  __shared__ alignas(16) unsigned short KtL[2][64 * 64];   // [k_t][d], fK-swizzled
  __shared__ alignas(16) unsigned short VtL[2][64 * 64];   // [d][k_t], fV-swizzled
  const int tid = threadIdx.x, lane = tid & 63, w = tid >> 6;  // w in [0,8)
  const int c = lane & 15, g = lane >> 4;
  const int bid = blockIdx.x;
  const int xcd = bid & 7, jj = bid >> 3;          // jj in [0,32)
  const int bh = xcd * 8 + (jj & 7), qp = jj >> 3; // bh [0,64), q-panel [0,4)
  const int b = bh >> 4, h = bh & 15;
  const bf16_t* Qh = Qg + (size_t)bh * T * 64;
  const bf16_t* Kh = Kg + (size_t)bh * T * 64;
  const bf16_t* Vh = Vtg + (size_t)bh * 64 * T;
  const int q0 = qp * 512 + w * 64;
  const int nkb = nkp[b];
  const int ntiles = (nkb + 63) >> 6;

  // Q fragments in registers (B-operand: col=q, k-elems = d)
  bf16x8 qfr[4][2];
#pragma unroll
  for (int qq = 0; qq < 4; ++qq)
#pragma unroll
    for (int dc = 0; dc < 2; ++dc)
      qfr[qq][dc] = *reinterpret_cast<const bf16x8*>(
          Qh + (size_t)(q0 + qq * 16 + c) * 64 + dc * 32 + g * 8);

  bf16x8 ones;
#pragma unroll
  for (int i = 0; i < 8; ++i) ones[i] = (bf16_t)1.0f;

  f32x4 oacc[4][4] = {};
  float lrun[4] = {0.f, 0.f, 0.f, 0.f};

  // 512 threads: one 16B chunk per thread per tile for K and V each.
  auto stage = [&](int t, int bi) {
    const int kt0 = t * 64;
    const int r = tid >> 3, p = tid & 7;
    const int lk = p ^ ((r & 3) | (((r >> 3) & 1) << 2));  // fK
    GLL16(Kh + (size_t)(kt0 + r) * 64 + lk * 8, &KtL[bi][w * 512]);
    const int lv = p ^ (r & 7);                            // fV
    GLL16(Vh + (size_t)r * T + kt0 + lv * 8, &VtL[bi][w * 512]);
  };

  stage(0, 0);
  __syncthreads();

  const int fK = (c & 3) | (((c >> 2) & 1) << 2);

  for (int t = 0; t < ntiles; ++t) {
    const int cur = t & 1;
    if (t + 1 < ntiles) stage(t + 1, cur ^ 1);

    bf16x8 kfr[4][2];
#pragma unroll
    for (int kr = 0; kr < 4; ++kr) {
      const int row = (c >> 2) * 8 + (kr & 1) * 4 + (c & 3) + (kr >> 1) * 32;
#pragma unroll
      for (int dc = 0; dc < 2; ++dc)
        kfr[kr][dc] = *reinterpret_cast<const bf16x8*>(
            &KtL[cur][row * 64 + (((dc * 4 + g) ^ fK) * 8)]);
    }

    const bool tail = (t == ntiles - 1) && (nkb & 63) != 0;
    f32x4 bias4[4];
#pragma unroll
    for (int kr = 0; kr < 4; ++kr) {
      if (tail) {
        const int kbase = t * 64 + g * 8 + (kr & 1) * 4 + (kr >> 1) * 32;
#pragma unroll
        for (int j = 0; j < 4; ++j) bias4[kr][j] = (kbase + j < nkb) ? 0.f : -1e30f;
      } else {
        bias4[kr][0] = bias4[kr][1] = bias4[kr][2] = bias4[kr][3] = 0.f;
      }
    }

    bf16x8 pfr[4][2];
#pragma unroll
    for (int qq = 0; qq < 4; ++qq) {
      f32x4 stq[4];
      __builtin_amdgcn_s_setprio(1);
#pragma unroll
      for (int kr = 0; kr < 4; ++kr) {
        f32x4 z = mfma16(kfr[kr][0], qfr[qq][0], bias4[kr]);
        stq[kr] = mfma16(kfr[kr][1], qfr[qq][1], z);
      }
      __builtin_amdgcn_s_setprio(0);
#pragma unroll
      for (int kc = 0; kc < 2; ++kc) {
        bf16x8 p;
#pragma unroll
        for (int j = 0; j < 4; ++j) {
          p[j]     = (bf16_t)__builtin_amdgcn_exp2f(stq[kc * 2 + 0][j]);
          p[4 + j] = (bf16_t)__builtin_amdgcn_exp2f(stq[kc * 2 + 1][j]);
        }
        pfr[qq][kc] = p;
      }
      f32x4 su = {0.f, 0.f, 0.f, 0.f};
      su = mfma16(ones, pfr[qq][0], su);
      su = mfma16(ones, pfr[qq][1], su);
      lrun[qq] += su[0];
    }

    __builtin_amdgcn_s_setprio(1);
#pragma unroll
    for (int df = 0; df < 4; ++df) {
      bf16x8 va[2];
#pragma unroll
      for (int kc = 0; kc < 2; ++kc) {
        const int r = df * 16 + c;
        va[kc] = *reinterpret_cast<const bf16x8*>(
            &VtL[cur][r * 64 + ((kc * 4 + g) ^ (r & 7)) * 8]);
      }
#pragma unroll
      for (int qq = 0; qq < 4; ++qq)
#pragma unroll
        for (int kc = 0; kc < 2; ++kc)
          oacc[df][qq] = mfma16(va[kc], pfr[qq][kc], oacc[df][qq]);
    }
    __builtin_amdgcn_s_setprio(0);
    __syncthreads();
  }

#pragma unroll
  for (int qq = 0; qq < 4; ++qq) {
    const float inv = 1.0f / lrun[qq];
    const int q = q0 + qq * 16 + c;
#pragma unroll
    for (int df = 0; df < 4; ++df) {
      bf16x4 bv;
#pragma unroll
      for (int j = 0; j < 4; ++j) bv[j] = (bf16_t)(oacc[df][qq][j] * inv);
      const int d0 = df * 16 + g * 4;
      *reinterpret_cast<bf16x4*>(aout + ((size_t)(b * 2048 + q)) * 1024 + h * 64 + d0) = bv;
    }
  }
}

// ---------------- launch ----------------
extern "C" void kernel_launch(void* const* d_in, const int* in_sizes, int n_in,
                              void* d_out, int out_size, void* d_ws, size_t ws_size,
                              hipStream_t stream) {
  (void)in_sizes; (void)n_in; (void)out_size; (void)ws_size;
  const float* x = (const float*)d_in[0];
  const int* pmask = (const int*)d_in[1];
  const float* wqkv = (const float*)d_in[2];
  const float* wproj = (const float*)d_in[3];
  float* out = (float*)d_out;
  char* ws = (char*)d_ws;

  bf16_t* xb    = (bf16_t*)(ws + 0);          // 16 MiB  [8192][1024]
  bf16_t* aob   = (bf16_t*)(ws + 0);          // overlay: attn out after x is dead
  bf16_t* wqkvb = (bf16_t*)(ws + 16777216);   // 6 MiB   [3072][1024]
  bf16_t* wprojb= (bf16_t*)(ws + 23068672);   // 2 MiB   [1024][1024]
  bf16_t* Qb    = (bf16_t*)(ws + 25165824);   // 16 MiB  [64][2048][64]
  bf16_t* Kb    = (bf16_t*)(ws + 41943040);   // 16 MiB  (compacted rows)
  bf16_t* Vtb   = (bf16_t*)(ws + 58720256);   // 16 MiB  [64][64][2048]

  int* tc  = (int*)d_out;            // 4*2048 ints (scratch in d_out)
  int* nkp = tc + 4 * 2048;          // 4 ints

  prep<<<12292, 256, 0, stream>>>(x, wqkv, wproj, xb, wqkvb, wprojb,
                                  pmask, tc, nkp, Kb, Vtb);

  gemm_ct<0><<<dim3(24, 64), 256, 0, stream>>>(wqkvb, xb, Qb, Kb, Vtb, nullptr, tc, nkp);
  attn_fwd<<<256, 512, 0, stream>>>(Qb, Kb, Vtb, nkp, aob);
  gemm_ct<1><<<dim3(8, 64), 256, 0, stream>>>(wprojb, aob, nullptr, nullptr, nullptr, out,
                                              nullptr, nullptr);
}

// Round 13
// 156.330 us; speedup vs baseline: 1.0894x; 1.0198x over previous
//
#include <hip/hip_runtime.h>
#include <hip/hip_bf16.h>
#include <stdint.h>

typedef __bf16 bf16_t;
typedef __bf16 bf16x8 __attribute__((ext_vector_type(8)));
typedef __bf16 bf16x4 __attribute__((ext_vector_type(4)));
typedef float f32x4 __attribute__((ext_vector_type(4)));

#define DEVFN static __device__ __forceinline__

DEVFN f32x4 mfma16(bf16x8 a, bf16x8 b, f32x4 c) {
  return __builtin_amdgcn_mfma_f32_16x16x32_bf16(a, b, c, 0, 0, 0);
}

// global -> LDS direct copy, 16B per lane; LDS dest must be wave-uniform.
#define GLL16(gsrc, ldst) __builtin_amdgcn_global_load_lds( \
    (__attribute__((address_space(1))) void*)(gsrc), \
    (__attribute__((address_space(3))) void*)(ldst), 16, 0, 0)

// softmax scale * log2(e), folded into Q at the QKV-GEMM epilogue
#define SCALE_Q 0.1803368801111204f

// ---------------- prep: fp32->bf16 conversion + key compaction (merged) ----------------
__global__ void prep(const float* __restrict__ x, const float* __restrict__ wqkv,
                     const float* __restrict__ wproj, bf16_t* __restrict__ xb,
                     bf16_t* __restrict__ wqkvb, bf16_t* __restrict__ wprojb,
                     const int* __restrict__ mask, int* __restrict__ tc,
                     int* __restrict__ nk, bf16_t* __restrict__ kb,
                     bf16_t* __restrict__ vtb) {
  const int tid = threadIdx.x;
  if (blockIdx.x < 12288) {
    const int i = blockIdx.x * 256 + tid;
    const float* s;
    bf16_t* d;
    int off;
    if (i < 2097152) { s = x; d = xb; off = i; }
    else if (i < 2097152 + 786432) { s = wqkv; d = wqkvb; off = i - 2097152; }
    else { s = wproj; d = wprojb; off = i - 2883584; }
    f32x4 v = reinterpret_cast<const f32x4*>(s)[off];
    bf16x4 o;
    o[0] = (bf16_t)v[0]; o[1] = (bf16_t)v[1]; o[2] = (bf16_t)v[2]; o[3] = (bf16_t)v[3];
    reinterpret_cast<bf16x4*>(d)[off] = o;
    return;
  }
  // ---- compaction ----
  const int b = blockIdx.x - 12288;
  const int lane = tid & 63, wv = tid >> 6;
  __shared__ int nk_s;
  const int* mrow = mask + b * 2048;
  if (wv == 0) {
    int base = 0;
    for (int cs = 0; cs < 2048; cs += 64) {
      const int mval = mrow[cs + lane];
      const unsigned long long bal = __ballot(mval == 0);
      const int pre = __popcll(bal & ((1ull << lane) - 1ull));
      if (!mval) tc[b * 2048 + base + pre] = cs + lane;
      base += __popcll(bal);
    }
    if (lane == 0) nk_s = base;
  }
  __syncthreads();
  const int nkb = nk_s;
  if (tid == 0) nk[b] = nkb;
  for (int i = nkb + tid; i < 2048; i += 256) tc[b * 2048 + i] = -1;
  const int ce = (nkb + 63) & ~63;
  for (int hh = wv; hh < 16; hh += 4) {
    const size_t bh = (size_t)(b * 16 + hh);
    for (int r = nkb; r < ce; ++r) {
      kb[(bh * 2048 + r) * 64 + lane] = (bf16_t)0.f;
      vtb[(bh * 64 + lane) * 2048 + r] = (bf16_t)0.f;
    }
  }
}

// ---------------- GEMM: C^T = A(W[O][K]) * B(x[M][K])^T ----------------
// R5-proven config: 128x128 tile, single-buffered, 32KB LDS, ~5 blocks/CU.
// EPI 0: QKV (grid 24x64). Q blocks (bx<8) dense; K/V blocks (bx>=8) gather
//        B-rows via tc (compacted keys), store K[BH][i][64] / Vt[BH][64][i].
// EPI 1: proj (grid 8x64), fp32 row-major out [M][1024].
template <int EPI>
__global__ __launch_bounds__(256, 2)
void gemm_ct(const bf16_t* __restrict__ A, const bf16_t* __restrict__ Bx,
             bf16_t* __restrict__ qb, bf16_t* __restrict__ kb,
             bf16_t* __restrict__ vtb, float* __restrict__ fout,
             const int* __restrict__ tc, const int* __restrict__ nkp) {
  constexpr int K = 1024;
  __shared__ alignas(16) unsigned short At[128 * 64];
  __shared__ alignas(16) unsigned short Bt[128 * 64];
  const int tid = threadIdx.x;
  const int lane = tid & 63, w = tid >> 6;
  const int c = lane & 15, g = lane >> 4;
  const int oBase = blockIdx.x * 128, mBase = blockIdx.y * 128;
  const int wo = (w >> 1) * 64, wm = (w & 1) * 64;

  int nkb = 0;
  bool kv = false;
  if (EPI == 0) {
    nkb = nkp[mBase >> 11];
    kv = (blockIdx.x >= 8);
    if (kv && (mBase & 2047) >= nkb) return;  // whole block is pad (uniform)
  }
  // per-lane B source rows (k-independent; gathered for K/V blocks)
  int brow[4];
#pragma unroll
  for (int i = 0; i < 4; ++i) {
    const int r = (i * 4 + w) * 8 + (lane >> 3);
    if (EPI == 0 && kv) {
      const int t = tc[(mBase >> 11) * 2048 + (mBase & 2047) + r];
      brow[i] = (mBase & ~2047) + (t < 0 ? 0 : t);
    } else {
      brow[i] = mBase + r;
    }
  }

  f32x4 acc[4][4] = {};

  for (int k0 = 0; k0 < K; k0 += 64) {
#pragma unroll
    for (int i = 0; i < 4; ++i) {
      const int cid = (i * 4 + w) * 64 + lane;
      const int r = cid >> 3;
      const int ss = (cid & 7) ^ (r & 7);  // pre-swizzled global source slot
      GLL16(A + (size_t)(oBase + r) * K + k0 + ss * 8, &At[(i * 4 + w) * 512]);
      GLL16(Bx + (size_t)brow[i] * K + k0 + ss * 8, &Bt[(i * 4 + w) * 512]);
    }
    __syncthreads();
    bf16x8 af[4][2], bfr[4][2];
#pragma unroll
    for (int f = 0; f < 4; ++f) {
#pragma unroll
      for (int kc = 0; kc < 2; ++kc) {
        const int ra = wo + f * 16 + c;
        af[f][kc] = *reinterpret_cast<const bf16x8*>(&At[ra * 64 + ((kc * 4 + g) ^ (ra & 7)) * 8]);
        const int rb = wm + f * 16 + c;
        bfr[f][kc] = *reinterpret_cast<const bf16x8*>(&Bt[rb * 64 + ((kc * 4 + g) ^ (rb & 7)) * 8]);
      }
    }
    __builtin_amdgcn_s_setprio(1);
#pragma unroll
    for (int of = 0; of < 4; ++of)
#pragma unroll
      for (int mf = 0; mf < 4; ++mf)
#pragma unroll
        for (int kc = 0; kc < 2; ++kc)
          acc[of][mf] = mfma16(af[of][kc], bfr[mf][kc], acc[of][mf]);
    __builtin_amdgcn_s_setprio(0);
    __syncthreads();
  }

#pragma unroll
  for (int of = 0; of < 4; ++of) {
    const int o0 = oBase + wo + of * 16 + g * 4;  // 4 consecutive o per lane
#pragma unroll
    for (int mf = 0; mf < 4; ++mf) {
      const int m = mBase + wm + mf * 16 + c;
      f32x4 v = acc[of][mf];
      if (EPI == 0) {
        if (!kv) {  // Q
          v[0] *= SCALE_Q; v[1] *= SCALE_Q; v[2] *= SCALE_Q; v[3] *= SCALE_Q;
          bf16x4 bv;
          bv[0] = (bf16_t)v[0]; bv[1] = (bf16_t)v[1]; bv[2] = (bf16_t)v[2]; bv[3] = (bf16_t)v[3];
          const int rem = o0 & 1023;
          const int h = rem >> 6, d0 = rem & 63;
          const int b = m >> 11, t = m & 2047;
          *reinterpret_cast<bf16x4*>(qb + (((size_t)(b * 16 + h)) * 2048 + t) * 64 + d0) = bv;
        } else {
          const int i = m & 2047;  // compact key index
          if (i < nkb) {
            bf16x4 bv;
            bv[0] = (bf16_t)v[0]; bv[1] = (bf16_t)v[1]; bv[2] = (bf16_t)v[2]; bv[3] = (bf16_t)v[3];
            const int rem = o0 & 1023;
            const int h = rem >> 6, d0 = rem & 63;
            const int b = m >> 11;
            const size_t bh = (size_t)(b * 16 + h);
            if (blockIdx.x < 16) {
              *reinterpret_cast<bf16x4*>(kb + (bh * 2048 + i) * 64 + d0) = bv;
            } else {
#pragma unroll
              for (int j = 0; j < 4; ++j)
                vtb[(bh * 64 + d0 + j) * 2048 + i] = bv[j];
            }
          }
        }
      } else {
        *reinterpret_cast<f32x4*>(fout + (size_t)m * 1024 + o0) = v;
      }
    }
  }
}

// ---------------- flash attention (compacted keys, no-max raw-exp softmax) ----------------
// Q (pre-scaled): [BH][T][64] ; K: [BH][i][64] ; Vt: [BH][64][i].
// 4 waves/block, 64 q-rows/wave (256 q per block). Flat grid 512, XCD-aware:
// the 8 q-panels of one bh land on one XCD (K/V stays in its L2).
__global__ __launch_bounds__(256, 2)
void attn_fwd(const bf16_t* __restrict__ Qg, const bf16_t* __restrict__ Kg,
              const bf16_t* __restrict__ Vtg, const int* __restrict__ nkp,
              bf16_t* __restrict__ aout) {
  constexpr int T = 2048;
  __shared__ alignas(16) unsigned short KtL[2][64 * 64];   // [k_t][d], fK-swizzled
  __shared__ alignas(16) unsigned short VtL[2][64 * 64];   // [d][k_t], fV-swizzled
  const int tid = threadIdx.x, lane = tid & 63, w = tid >> 6;
  const int c = lane & 15, g = lane >> 4;
  const int bid = blockIdx.x;
  const int xcd = bid & 7, jj = bid >> 3;
  const int bh = xcd * 8 + (jj & 7), qp = jj >> 3;  // bh [0,64), q-panel [0,8)
  const int b = bh >> 4, h = bh & 15;
  const bf16_t* Qh = Qg + (size_t)bh * T * 64;
  const bf16_t* Kh = Kg + (size_t)bh * T * 64;
  const bf16_t* Vh = Vtg + (size_t)bh * 64 * T;
  const int q0 = qp * 256 + w * 64;
  const int nkb = nkp[b];
  const int ntiles = (nkb + 63) >> 6;

  bf16x8 qfr[4][2];
#pragma unroll
  for (int qq = 0; qq < 4; ++qq)
#pragma unroll
    for (int dc = 0; dc < 2; ++dc)
      qfr[qq][dc] = *reinterpret_cast<const bf16x8*>(
          Qh + (size_t)(q0 + qq * 16 + c) * 64 + dc * 32 + g * 8);

  bf16x8 ones;
#pragma unroll
  for (int i = 0; i < 8; ++i) ones[i] = (bf16_t)1.0f;

  f32x4 oacc[4][4] = {};
  float lrun[4] = {0.f, 0.f, 0.f, 0.f};

  auto stage = [&](int t, int bi) {
    const int kt0 = t * 64;
#pragma unroll
    for (int i = 0; i < 2; ++i) {
      const int cid = (i * 4 + w) * 64 + lane;
      const int r = cid >> 3, p = cid & 7;
      const int lk = p ^ ((r & 3) | (((r >> 3) & 1) << 2));  // fK
      GLL16(Kh + (size_t)(kt0 + r) * 64 + lk * 8, &KtL[bi][(i * 4 + w) * 512]);
      const int lv = p ^ (r & 7);                            // fV
      GLL16(Vh + (size_t)r * T + kt0 + lv * 8, &VtL[bi][(i * 4 + w) * 512]);
    }
  };

  stage(0, 0);
  __syncthreads();

  const int fK = (c & 3) | (((c >> 2) & 1) << 2);

  for (int t = 0; t < ntiles; ++t) {
    const int cur = t & 1;
    if (t + 1 < ntiles) stage(t + 1, cur ^ 1);

    bf16x8 kfr[4][2];
#pragma unroll
    for (int kr = 0; kr < 4; ++kr) {
      const int row = (c >> 2) * 8 + (kr & 1) * 4 + (c & 3) + (kr >> 1) * 32;
#pragma unroll
      for (int dc = 0; dc < 2; ++dc)
        kfr[kr][dc] = *reinterpret_cast<const bf16x8*>(
            &KtL[cur][row * 64 + (((dc * 4 + g) ^ fK) * 8)]);
    }

    const bool tail = (t == ntiles - 1) && (nkb & 63) != 0;
    f32x4 bias4[4];
#pragma unroll
    for (int kr = 0; kr < 4; ++kr) {
      if (tail) {
        const int kbase = t * 64 + g * 8 + (kr & 1) * 4 + (kr >> 1) * 32;
#pragma unroll
        for (int j = 0; j < 4; ++j) bias4[kr][j] = (kbase + j < nkb) ? 0.f : -1e30f;
      } else {
        bias4[kr][0] = bias4[kr][1] = bias4[kr][2] = bias4[kr][3] = 0.f;
      }
    }

    bf16x8 pfr[4][2];
#pragma unroll
    for (int qq = 0; qq < 4; ++qq) {
      f32x4 stq[4];
      __builtin_amdgcn_s_setprio(1);
#pragma unroll
      for (int kr = 0; kr < 4; ++kr) {
        f32x4 z = mfma16(kfr[kr][0], qfr[qq][0], bias4[kr]);
        stq[kr] = mfma16(kfr[kr][1], qfr[qq][1], z);
      }
      __builtin_amdgcn_s_setprio(0);
#pragma unroll
      for (int kc = 0; kc < 2; ++kc) {
        bf16x8 p;
#pragma unroll
        for (int j = 0; j < 4; ++j) {
          p[j]     = (bf16_t)__builtin_amdgcn_exp2f(stq[kc * 2 + 0][j]);
          p[4 + j] = (bf16_t)__builtin_amdgcn_exp2f(stq[kc * 2 + 1][j]);
        }
        pfr[qq][kc] = p;
      }
      f32x4 su = {0.f, 0.f, 0.f, 0.f};
      su = mfma16(ones, pfr[qq][0], su);
      su = mfma16(ones, pfr[qq][1], su);
      lrun[qq] += su[0];
    }

    __builtin_amdgcn_s_setprio(1);
#pragma unroll
    for (int df = 0; df < 4; ++df) {
      bf16x8 va[2];
#pragma unroll
      for (int kc = 0; kc < 2; ++kc) {
        const int r = df * 16 + c;
        va[kc] = *reinterpret_cast<const bf16x8*>(
            &VtL[cur][r * 64 + ((kc * 4 + g) ^ (r & 7)) * 8]);
      }
#pragma unroll
      for (int qq = 0; qq < 4; ++qq)
#pragma unroll
        for (int kc = 0; kc < 2; ++kc)
          oacc[df][qq] = mfma16(va[kc], pfr[qq][kc], oacc[df][qq]);
    }
    __builtin_amdgcn_s_setprio(0);
    __syncthreads();
  }

#pragma unroll
  for (int qq = 0; qq < 4; ++qq) {
    const float inv = 1.0f / lrun[qq];
    const int q = q0 + qq * 16 + c;
#pragma unroll
    for (int df = 0; df < 4; ++df) {
      bf16x4 bv;
#pragma unroll
      for (int j = 0; j < 4; ++j) bv[j] = (bf16_t)(oacc[df][qq][j] * inv);
      const int d0 = df * 16 + g * 4;
      *reinterpret_cast<bf16x4*>(aout + ((size_t)(b * 2048 + q)) * 1024 + h * 64 + d0) = bv;
    }
  }
}

// ---------------- launch ----------------
extern "C" void kernel_launch(void* const* d_in, const int* in_sizes, int n_in,
                              void* d_out, int out_size, void* d_ws, size_t ws_size,
                              hipStream_t stream) {
  (void)in_sizes; (void)n_in; (void)out_size; (void)ws_size;
  const float* x = (const float*)d_in[0];
  const int* pmask = (const int*)d_in[1];
  const float* wqkv = (const float*)d_in[2];
  const float* wproj = (const float*)d_in[3];
  float* out = (float*)d_out;
  char* ws = (char*)d_ws;

  bf16_t* xb    = (bf16_t*)(ws + 0);          // 16 MiB  [8192][1024]
  bf16_t* aob   = (bf16_t*)(ws + 0);          // overlay: attn out after x is dead
  bf16_t* wqkvb = (bf16_t*)(ws + 16777216);   // 6 MiB   [3072][1024]
  bf16_t* wprojb= (bf16_t*)(ws + 23068672);   // 2 MiB   [1024][1024]
  bf16_t* Qb    = (bf16_t*)(ws + 25165824);   // 16 MiB  [64][2048][64]
  bf16_t* Kb    = (bf16_t*)(ws + 41943040);   // 16 MiB  (compacted rows)
  bf16_t* Vtb   = (bf16_t*)(ws + 58720256);   // 16 MiB  [64][64][2048]

  int* tc  = (int*)d_out;            // 4*2048 ints (scratch in d_out)
  int* nkp = tc + 4 * 2048;          // 4 ints

  prep<<<12292, 256, 0, stream>>>(x, wqkv, wproj, xb, wqkvb, wprojb,
                                  pmask, tc, nkp, Kb, Vtb);

  gemm_ct<0><<<dim3(24, 64), 256, 0, stream>>>(wqkvb, xb, Qb, Kb, Vtb, nullptr, tc, nkp);
  attn_fwd<<<512, 256, 0, stream>>>(Qb, Kb, Vtb, nkp, aob);
  gemm_ct<1><<<dim3(8, 64), 256, 0, stream>>>(wprojb, aob, nullptr, nullptr, nullptr, out,
                                              nullptr, nullptr);
}